// Round 11
// baseline (145.065 us; speedup 1.0000x reference)
//
#include <hip/hip_runtime.h>
#include <cstdint>

// NeuralRadiance via bf16 MFMA (16x16x32). Round 11 = round 10 UNJAMMED:
// single dependency chain per sub (4 subs/tile) to halve the live
// accumulator set (~32 AGPRs back), raising resident waves/SIMD from 2
// toward 4 -- r10 evidence: wall 2060 cyc/tile vs 1040 issue cyc at only
// 2 waves/SIMD (occ 25%). Keeps: permlane-free Lam-permuted weights (setup
// kernel), W2 fragments streamed from LDS, staged pos/nrm + emb prefetch,
// launch_bounds(256,4) (cap 128; weight frags remat-able from global ws).
// Layout facts (HW-verified): A-frag lane holds A[m=lane&15][k=quad*8+j];
// B-frag B[k=quad*8+j][n=lane&15]; C/D reg r = D[m=quad*4+r][n=lane&15].
// Lam(k) = 32*(k>>5) + 16*((k>>2)&1) + 4*((k>>3)&3) + (k&3): position k of
// the relu+packed D-regs holds logical feature Lam(k); W2/W3 input rows are
// pre-permuted so packed D IS the next layer's fragment.

typedef short  bf16x8 __attribute__((ext_vector_type(8)));
typedef float  f32x4  __attribute__((ext_vector_type(4)));

#define MFMA16(A, B, C) __builtin_amdgcn_mfma_f32_16x16x32_bf16((A), (B), (C), 0, 0, 0)

// guaranteed-HW packed cvt: 2 f32 -> dword of 2 bf16 (lo=a, hi=b), RNE
__device__ inline int pk(float a, float b) {
    int d;
    __asm__("v_cvt_pk_bf16_f32 %0, %1, %2" : "=v"(d) : "v"(a), "v"(b));
    return d;
}

// compile-time ordering only (DS pipe is in-order per wave; validated r4-r10)
__device__ inline void cfence() { __asm__ volatile("" ::: "memory"); }

__device__ inline float sigmoid_fast(float x) {
    float e = __expf(-x);
    return __builtin_amdgcn_rcpf(1.0f + e);
}

// logical feature held at k-position k of the packed-D fragment
__device__ inline int lam(int k) {
    return 32 * (k >> 5) + 16 * ((k >> 2) & 1) + 4 * ((k >> 3) & 3) + (k & 3);
}

// C/D accs (4x f32x4) -> next-layer frag halves: relu + pack ONLY.
__device__ inline void cd_pack(const f32x4 acc[4], int4& lo, int4& hi) {
    lo = make_int4(pk(fmaxf(acc[0][0],0.f), fmaxf(acc[0][1],0.f)),
                   pk(fmaxf(acc[0][2],0.f), fmaxf(acc[0][3],0.f)),
                   pk(fmaxf(acc[1][0],0.f), fmaxf(acc[1][1],0.f)),
                   pk(fmaxf(acc[1][2],0.f), fmaxf(acc[1][3],0.f)));
    hi = make_int4(pk(fmaxf(acc[2][0],0.f), fmaxf(acc[2][1],0.f)),
                   pk(fmaxf(acc[2][2],0.f), fmaxf(acc[2][3],0.f)),
                   pk(fmaxf(acc[3][0],0.f), fmaxf(acc[3][1],0.f)),
                   pk(fmaxf(acc[3][2],0.f), fmaxf(acc[3][3],0.f)));
}

__device__ inline bf16x8 as_frag(int4 v) {
    bf16x8 f; __builtin_memcpy(&f, &v, sizeof(f)); return f;
}

#define XS 40   // xbuf row stride in shorts (20 dwords; b128 at bank floor)

// ---- setup: fragment-ordered bf16 weights in ws (int4 units):
//   ws[0..255]   : w1 frags [t*64+lane]          (identity out-feats)
//   ws[256..767] : w2 frags [(t*2+ks)*64+lane]   (input rows permuted by lam)
//   ws[768..895] : w3 frags [h*64+lane]          (input rows permuted by lam)
__global__ __launch_bounds__(256) void nrad_setup_kernel(
    const float* __restrict__ W1, const float* __restrict__ b1,
    const float* __restrict__ W2, const float* __restrict__ W3,
    float* __restrict__ ws)
{
    const int tid  = threadIdx.x;
    const int wv   = tid >> 6;
    const int lane = tid & 63;
    const int q    = lane >> 4;
    const int nn   = lane & 15;
    int4* w1o = (int4*)ws;
    int4* w2o = (int4*)ws + 256;
    int4* w3o = (int4*)ws + 768;

    if (wv == 0) {
        // A-frag of W1T tile t: A[m=nn][k=q*8+j]; k<19=W1, k==19=b1, else 0
        for (int t = 0; t < 4; ++t) {
            int n = t * 16 + nn;
            float v[8];
            #pragma unroll
            for (int j = 0; j < 8; ++j) {
                int k = q * 8 + j;
                v[j] = (k < 19) ? W1[k * 64 + n] : (k == 19 ? b1[n] : 0.0f);
            }
            w1o[t * 64 + lane] = make_int4(pk(v[0],v[1]), pk(v[2],v[3]),
                                           pk(v[4],v[5]), pk(v[6],v[7]));
        }
    } else if (wv == 3) {
        // B-frag of W3 (rows permuted by lam; cols zero-padded past 3)
        for (int h = 0; h < 2; ++h) {
            float v[8];
            #pragma unroll
            for (int j = 0; j < 8; ++j) {
                int kin = lam(h * 32 + q * 8 + j);
                v[j] = (nn < 3) ? W3[kin * 3 + nn] : 0.0f;
            }
            w3o[h * 64 + lane] = make_int4(pk(v[0],v[1]), pk(v[2],v[3]),
                                           pk(v[4],v[5]), pk(v[6],v[7]));
        }
    } else {
        // A-frag of W2T tile (t,ks): A[m=nn][k] = W2[lam(k)][t*16+nn]
        for (int tt = 0; tt < 2; ++tt) {
            int t = (wv - 1) * 2 + tt;
            int n = t * 16 + nn;
            for (int ks = 0; ks < 2; ++ks) {
                float v[8];
                #pragma unroll
                for (int j = 0; j < 8; ++j) {
                    int kin = lam(ks * 32 + q * 8 + j);
                    v[j] = W2[kin * 64 + n];
                }
                w2o[(t * 2 + ks) * 64 + lane] = make_int4(pk(v[0],v[1]), pk(v[2],v[3]),
                                                          pk(v[4],v[5]), pk(v[6],v[7]));
            }
        }
    }
}

__global__ __launch_bounds__(256, 4) void nrad_mfma_kernel(
    const float* __restrict__ pos, const float* __restrict__ nrm,
    const float* __restrict__ emb,
    const float* __restrict__ b2, const float* __restrict__ b3,
    const float* __restrict__ ws, float* __restrict__ out, int ntiles)
{
    // w2lds: 8 frags x 64 lanes x 16B = 8KB [frag][lane] (conflict-free);
    // xbuf : per-wave x staging (4 x 5120 B).
    __shared__ alignas(16) int4  w2lds[512];
    __shared__ alignas(16) short xbuf[4][64 * XS];

    const int tid  = threadIdx.x;
    const int wave = tid >> 6;
    const int lane = tid & 63;
    const int q    = lane >> 4;
    const int nn   = lane & 15;

    // ---- stage W2 fragments into LDS
    const int4* wsf = (const int4*)ws;
    w2lds[tid]       = wsf[256 + tid];
    w2lds[tid + 256] = wsf[512 + tid];
    __syncthreads();

    // ---- register fragments: w1, w3 (w2 streams from LDS; remat-able from ws)
    bf16x8 w1f[4], w3f[2];
    #pragma unroll
    for (int t = 0; t < 4; ++t) w1f[t] = as_frag(wsf[t * 64 + lane]);
    w3f[0] = as_frag(wsf[768 + lane]);
    w3f[1] = as_frag(wsf[832 + lane]);
    f32x4 b2rv[4];
    #pragma unroll
    for (int t = 0; t < 4; ++t) b2rv[t] = *(const f32x4*)(b2 + t * 16 + q * 4);
    const float b3r = (nn < 3) ? b3[nn] : 0.0f;

    short* xw = &xbuf[wave][0];
    const int4* w2l = w2lds + lane;      // + (t*2+ks)*64
    const int xro  = nn * XS + q * 8;    // + sub*16*XS : L1 B-frag read
    const int oofs = q * 12 + nn;        // out: (q*4+r)*3+nn, r via stride 3

    const int wave_gid = blockIdx.x * 4 + wave;
    const int nwaves   = gridDim.x * 4;
    const float4* emb4 = (const float4*)emb;

    // ---- prefetch state (loop-carried): normal + gathered embedding
    float n0 = 0, n1 = 0, n2 = 0;
    float4 f0{}, f1{}, f2{}, f3{};
    if (wave_gid < ntiles) {
        int i = wave_gid * 64 + lane;
        float p0 = pos[3*i], p1 = pos[3*i+1], p2 = pos[3*i+2];
        n0 = nrm[3*i]; n1 = nrm[3*i+1]; n2 = nrm[3*i+2];
        int s0 = (int)(p0 * 8.0f), s1 = (int)(p1 * 8.0f), s2 = (int)(p2 * 8.0f);
        uint32_t h = ((uint32_t)s0 * 73856093u) ^ ((uint32_t)s1 * 19349663u) ^
                     ((uint32_t)s2 * 83492791u);
        uint32_t idx = h & 32767u;
        f0 = emb4[idx*4+0]; f1 = emb4[idx*4+1];
        f2 = emb4[idx*4+2]; f3 = emb4[idx*4+3];
    }

    for (int tile = wave_gid; tile < ntiles; tile += nwaves) {
        const int base = tile * 64;
        const float* ob = out + (size_t)base * 3;
        const f32x4 z = {0.0f, 0.0f, 0.0f, 0.0f};

        // ---- pack prefetched point into xbuf row = lane
        {
            int4 A = make_int4(pk(f0.x, f0.y), pk(f0.z, f0.w), pk(f1.x, f1.y), pk(f1.z, f1.w));
            int4 B = make_int4(pk(f2.x, f2.y), pk(f2.z, f2.w), pk(f3.x, f3.y), pk(f3.z, f3.w));
            int4 C = make_int4(pk(n0, n1), pk(n2, 1.0f), 0, 0);  // k=19 -> 1.0 (bias)
            int4 D = make_int4(0, 0, 0, 0);
            int4* xr = (int4*)(xw + lane * XS);
            xr[0] = A; xr[1] = B; xr[2] = C; xr[3] = D;
        }
        cfence();

        // ---- stage A: issue next tile's pos/nrm loads
        int nt = tile + nwaves;
        int lt = (nt < ntiles) ? nt : tile;   // wave-uniform clamp
        int inext = lt * 64 + lane;
        float q0 = pos[3*inext], q1 = pos[3*inext+1], q2 = pos[3*inext+2];
        n0 = nrm[3*inext]; n1 = nrm[3*inext+1]; n2 = nrm[3*inext+2];

        // ---- one sub-tile, single dependency chain
        auto do_sub = [&](int sub) {
            bf16x8 xf = *(const bf16x8*)(xw + sub * 16 * XS + xro);

            f32x4 a1[4];
            #pragma unroll
            for (int t = 0; t < 4; ++t) a1[t] = MFMA16(w1f[t], xf, z);

            int4 lo, hi;
            cd_pack(a1, lo, hi);
            bf16x8 h1f0 = as_frag(lo), h1f1 = as_frag(hi);

            f32x4 a2[4];
            #pragma unroll
            for (int t = 0; t < 4; ++t) {
                bf16x8 w20 = as_frag(w2l[(t * 2 + 0) * 64]);
                bf16x8 w21 = as_frag(w2l[(t * 2 + 1) * 64]);
                f32x4 c = MFMA16(w20, h1f0, b2rv[t]);
                a2[t]   = MFMA16(w21, h1f1, c);
            }

            cd_pack(a2, lo, hi);
            bf16x8 h2f0 = as_frag(lo), h2f1 = as_frag(hi);

            f32x4 cb = {b3r, b3r, b3r, b3r};
            f32x4 acc3 = MFMA16(h2f1, w3f[1], MFMA16(h2f0, w3f[0], cb));

            float o0 = sigmoid_fast(acc3[0]), o1 = sigmoid_fast(acc3[1]);
            float o2 = sigmoid_fast(acc3[2]), o3 = sigmoid_fast(acc3[3]);
            if (nn < 3) {
                float* o = (float*)(ob + sub * 48 + oofs);
                o[0] = o0; o[3] = o1; o[6] = o2; o[9] = o3;
            }
        };

        do_sub(0);
        do_sub(1);

        // ---- stage B: hash from prefetched pos, issue emb gather
        {
            int s0 = (int)(q0 * 8.0f), s1 = (int)(q1 * 8.0f), s2 = (int)(q2 * 8.0f);
            uint32_t h = ((uint32_t)s0 * 73856093u) ^ ((uint32_t)s1 * 19349663u) ^
                         ((uint32_t)s2 * 83492791u);
            uint32_t idx = h & 32767u;
            f0 = emb4[idx*4+0]; f1 = emb4[idx*4+1];
            f2 = emb4[idx*4+2]; f3 = emb4[idx*4+3];
        }

        do_sub(2);
        do_sub(3);

        cfence();   // next tile's xbuf writes stay behind this tile's reads
    }
}

extern "C" void kernel_launch(void* const* d_in, const int* in_sizes, int n_in,
                              void* d_out, int out_size, void* d_ws, size_t ws_size,
                              hipStream_t stream) {
    const float* pos = (const float*)d_in[0];
    const float* nrm = (const float*)d_in[1];
    const float* emb = (const float*)d_in[2];
    const float* W1  = (const float*)d_in[3];
    const float* b1  = (const float*)d_in[4];
    const float* W2  = (const float*)d_in[5];
    const float* b2  = (const float*)d_in[6];
    const float* W3  = (const float*)d_in[7];
    const float* b3  = (const float*)d_in[8];
    float* out = (float*)d_out;
    float* ws  = (float*)d_ws;   // 896 int4 = 14336 B used

    int n = in_sizes[0] / 3;      // 2,097,152
    int ntiles = n / 64;          // 32768

    nrad_setup_kernel<<<1, 256, 0, stream>>>(W1, b1, W2, W3, ws);
    nrad_mfma_kernel<<<2048, 256, 0, stream>>>(pos, nrm, emb, b2, b3, ws,
                                               out, ntiles);
}

// Round 14
// 140.953 us; speedup vs baseline: 1.0292x; 1.0292x over previous
//
#include <hip/hip_runtime.h>
#include <cstdint>

// NeuralRadiance via bf16 MFMA (16x16x32). Round 14 = round 10 (verified
// best, 54.7us) re-anchored after two NaN failures of the packed-int16 relu
// (r12 asm, r13 builtin -- both NaN; pitfall logged, relu stays as fmaxf in
// float domain). Only change vs r10: xbuf's constant region (shorts 20..31
// of each row: C zero tail + D dword) is zeroed ONCE before the loop; the
// per-tile staging writes only A(b128) + B(b128) + C(b64).
// Keeps: jammed 2-sub ILP pairs, permlane-free Lam-permuted weights, W2
// fragments streamed from LDS, staged pos/nrm + emb prefetch, grid 2048,
// launch_bounds(256,3).
// Layout facts (HW-verified): A-frag lane holds A[m=lane&15][k=quad*8+j];
// B-frag B[k=quad*8+j][n=lane&15]; C/D reg r = D[m=quad*4+r][n=lane&15].
// Lam(k) = 32*(k>>5) + 16*((k>>2)&1) + 4*((k>>3)&3) + (k&3): position k of
// the relu+packed D-regs holds logical feature Lam(k); W2/W3 input rows are
// pre-permuted so packed D IS the next layer's fragment.

typedef short  bf16x8 __attribute__((ext_vector_type(8)));
typedef float  f32x4  __attribute__((ext_vector_type(4)));

#define MFMA16(A, B, C) __builtin_amdgcn_mfma_f32_16x16x32_bf16((A), (B), (C), 0, 0, 0)

// guaranteed-HW packed cvt: 2 f32 -> dword of 2 bf16 (lo=a, hi=b), RNE
__device__ inline int pk(float a, float b) {
    int d;
    __asm__("v_cvt_pk_bf16_f32 %0, %1, %2" : "=v"(d) : "v"(a), "v"(b));
    return d;
}

// compile-time ordering only (DS pipe is in-order per wave; validated r4-r11)
__device__ inline void cfence() { __asm__ volatile("" ::: "memory"); }

__device__ inline float sigmoid_fast(float x) {
    float e = __expf(-x);
    return __builtin_amdgcn_rcpf(1.0f + e);
}

// logical feature held at k-position k of the packed-D fragment
__device__ inline int lam(int k) {
    return 32 * (k >> 5) + 16 * ((k >> 2) & 1) + 4 * ((k >> 3) & 3) + (k & 3);
}

// C/D accs (4x f32x4) -> next-layer frag halves: float relu + pack (verified r10).
__device__ inline void cd_pack(const f32x4 acc[4], int4& lo, int4& hi) {
    lo = make_int4(pk(fmaxf(acc[0][0],0.f), fmaxf(acc[0][1],0.f)),
                   pk(fmaxf(acc[0][2],0.f), fmaxf(acc[0][3],0.f)),
                   pk(fmaxf(acc[1][0],0.f), fmaxf(acc[1][1],0.f)),
                   pk(fmaxf(acc[1][2],0.f), fmaxf(acc[1][3],0.f)));
    hi = make_int4(pk(fmaxf(acc[2][0],0.f), fmaxf(acc[2][1],0.f)),
                   pk(fmaxf(acc[2][2],0.f), fmaxf(acc[2][3],0.f)),
                   pk(fmaxf(acc[3][0],0.f), fmaxf(acc[3][1],0.f)),
                   pk(fmaxf(acc[3][2],0.f), fmaxf(acc[3][3],0.f)));
}

__device__ inline bf16x8 as_frag(int4 v) {
    bf16x8 f; __builtin_memcpy(&f, &v, sizeof(f)); return f;
}

#define XS 40   // xbuf row stride in shorts (20 dwords; b128 at bank floor)

// ---- setup: fragment-ordered bf16 weights in ws (int4 units):
//   ws[0..255]   : w1 frags [t*64+lane]          (identity out-feats)
//   ws[256..767] : w2 frags [(t*2+ks)*64+lane]   (input rows permuted by lam)
//   ws[768..895] : w3 frags [h*64+lane]          (input rows permuted by lam)
__global__ __launch_bounds__(256) void nrad_setup_kernel(
    const float* __restrict__ W1, const float* __restrict__ b1,
    const float* __restrict__ W2, const float* __restrict__ W3,
    float* __restrict__ ws)
{
    const int tid  = threadIdx.x;
    const int wv   = tid >> 6;
    const int lane = tid & 63;
    const int q    = lane >> 4;
    const int nn   = lane & 15;
    int4* w1o = (int4*)ws;
    int4* w2o = (int4*)ws + 256;
    int4* w3o = (int4*)ws + 768;

    if (wv == 0) {
        // A-frag of W1T tile t: A[m=nn][k=q*8+j]; k<19=W1, k==19=b1, else 0
        for (int t = 0; t < 4; ++t) {
            int n = t * 16 + nn;
            float v[8];
            #pragma unroll
            for (int j = 0; j < 8; ++j) {
                int k = q * 8 + j;
                v[j] = (k < 19) ? W1[k * 64 + n] : (k == 19 ? b1[n] : 0.0f);
            }
            w1o[t * 64 + lane] = make_int4(pk(v[0],v[1]), pk(v[2],v[3]),
                                           pk(v[4],v[5]), pk(v[6],v[7]));
        }
    } else if (wv == 3) {
        // B-frag of W3 (rows permuted by lam; cols zero-padded past 3)
        for (int h = 0; h < 2; ++h) {
            float v[8];
            #pragma unroll
            for (int j = 0; j < 8; ++j) {
                int kin = lam(h * 32 + q * 8 + j);
                v[j] = (nn < 3) ? W3[kin * 3 + nn] : 0.0f;
            }
            w3o[h * 64 + lane] = make_int4(pk(v[0],v[1]), pk(v[2],v[3]),
                                           pk(v[4],v[5]), pk(v[6],v[7]));
        }
    } else {
        // A-frag of W2T tile (t,ks): A[m=nn][k] = W2[lam(k)][t*16+nn]
        for (int tt = 0; tt < 2; ++tt) {
            int t = (wv - 1) * 2 + tt;
            int n = t * 16 + nn;
            for (int ks = 0; ks < 2; ++ks) {
                float v[8];
                #pragma unroll
                for (int j = 0; j < 8; ++j) {
                    int kin = lam(ks * 32 + q * 8 + j);
                    v[j] = W2[kin * 64 + n];
                }
                w2o[(t * 2 + ks) * 64 + lane] = make_int4(pk(v[0],v[1]), pk(v[2],v[3]),
                                                          pk(v[4],v[5]), pk(v[6],v[7]));
            }
        }
    }
}

__global__ __launch_bounds__(256, 3) void nrad_mfma_kernel(
    const float* __restrict__ pos, const float* __restrict__ nrm,
    const float* __restrict__ emb,
    const float* __restrict__ b2, const float* __restrict__ b3,
    const float* __restrict__ ws, float* __restrict__ out, int ntiles)
{
    // w2lds: 8 frags x 64 lanes x 16B = 8KB [frag][lane] (conflict-free);
    // xbuf : per-wave x staging.
    __shared__ alignas(16) int4  w2lds[512];
    __shared__ alignas(16) short xbuf[4][64 * XS];

    const int tid  = threadIdx.x;
    const int wave = tid >> 6;
    const int lane = tid & 63;
    const int q    = lane >> 4;
    const int nn   = lane & 15;

    // ---- stage W2 fragments into LDS
    const int4* wsf = (const int4*)ws;
    w2lds[tid]       = wsf[256 + tid];
    w2lds[tid + 256] = wsf[512 + tid];
    __syncthreads();

    // ---- register fragments: w1, w3 (w2 streams from LDS)
    bf16x8 w1f[4], w3f[2];
    #pragma unroll
    for (int t = 0; t < 4; ++t) w1f[t] = as_frag(wsf[t * 64 + lane]);
    w3f[0] = as_frag(wsf[768 + lane]);
    w3f[1] = as_frag(wsf[832 + lane]);
    f32x4 b2rv[4];
    #pragma unroll
    for (int t = 0; t < 4; ++t) b2rv[t] = *(const f32x4*)(b2 + t * 16 + q * 4);
    const float b3r = (nn < 3) ? b3[nn] : 0.0f;

    short* xw = &xbuf[wave][0];
    const int4* w2l = w2lds + lane;      // + (t*2+ks)*64
    const int xro  = nn * XS + q * 8;    // + sub*16*XS : L1 B-frag read
    const int oofs = q * 12 + nn;        // out: (q*4+r)*3+nn, r via stride 3

    // ---- one-time: zero the constant region of this wave's xbuf rows
    // (shorts 20..31 = C zero tail + D dword; never touched per-tile)
    {
        int* zp = (int*)(xw + lane * XS);
        zp[10] = 0; zp[11] = 0;          // shorts 20..23
        *(int4*)(xw + lane * XS + 24) = make_int4(0, 0, 0, 0);  // shorts 24..31
    }

    const int wave_gid = blockIdx.x * 4 + wave;
    const int nwaves   = gridDim.x * 4;
    const float4* emb4 = (const float4*)emb;

    // ---- prefetch state (loop-carried): normal + gathered embedding
    float n0 = 0, n1 = 0, n2 = 0;
    float4 f0{}, f1{}, f2{}, f3{};
    if (wave_gid < ntiles) {
        int i = wave_gid * 64 + lane;
        float p0 = pos[3*i], p1 = pos[3*i+1], p2 = pos[3*i+2];
        n0 = nrm[3*i]; n1 = nrm[3*i+1]; n2 = nrm[3*i+2];
        int s0 = (int)(p0 * 8.0f), s1 = (int)(p1 * 8.0f), s2 = (int)(p2 * 8.0f);
        uint32_t h = ((uint32_t)s0 * 73856093u) ^ ((uint32_t)s1 * 19349663u) ^
                     ((uint32_t)s2 * 83492791u);
        uint32_t idx = h & 32767u;
        f0 = emb4[idx*4+0]; f1 = emb4[idx*4+1];
        f2 = emb4[idx*4+2]; f3 = emb4[idx*4+3];
    }

    for (int tile = wave_gid; tile < ntiles; tile += nwaves) {
        const int base = tile * 64;
        const float* ob = out + (size_t)base * 3;
        const f32x4 z = {0.0f, 0.0f, 0.0f, 0.0f};

        // ---- pack prefetched point into xbuf row = lane (A,B,C only)
        {
            int4 A = make_int4(pk(f0.x, f0.y), pk(f0.z, f0.w), pk(f1.x, f1.y), pk(f1.z, f1.w));
            int4 B = make_int4(pk(f2.x, f2.y), pk(f2.z, f2.w), pk(f3.x, f3.y), pk(f3.z, f3.w));
            int2 C = make_int2(pk(n0, n1), pk(n2, 1.0f));   // k=19 -> 1.0 (bias)
            int4* xr = (int4*)(xw + lane * XS);
            xr[0] = A; xr[1] = B;
            *(int2*)(xw + lane * XS + 16) = C;
        }
        cfence();

        // ---- stage A: issue next tile's pos/nrm loads
        int nt = tile + nwaves;
        int lt = (nt < ntiles) ? nt : tile;   // wave-uniform clamp
        int inext = lt * 64 + lane;
        float q0 = pos[3*inext], q1 = pos[3*inext+1], q2 = pos[3*inext+2];
        n0 = nrm[3*inext]; n1 = nrm[3*inext+1]; n2 = nrm[3*inext+2];

        // ---- one jammed sub-pair (subs 2sp, 2sp+1): two independent chains
        auto do_pair = [&](int sp) {
            bf16x8 xfA = *(const bf16x8*)(xw + (2*sp)     * 16 * XS + xro);
            bf16x8 xfB = *(const bf16x8*)(xw + (2*sp + 1) * 16 * XS + xro);

            f32x4 a1A[4], a1B[4];
            #pragma unroll
            for (int t = 0; t < 4; ++t) a1A[t] = MFMA16(w1f[t], xfA, z);
            #pragma unroll
            for (int t = 0; t < 4; ++t) a1B[t] = MFMA16(w1f[t], xfB, z);

            int4 lA, hA, lB, hB;
            cd_pack(a1A, lA, hA);
            cd_pack(a1B, lB, hB);
            bf16x8 h1A0 = as_frag(lA), h1A1 = as_frag(hA);
            bf16x8 h1B0 = as_frag(lB), h1B1 = as_frag(hB);

            f32x4 a2A[4], a2B[4];
            #pragma unroll
            for (int t = 0; t < 4; ++t) {
                bf16x8 w20 = as_frag(w2l[(t * 2 + 0) * 64]);
                bf16x8 w21 = as_frag(w2l[(t * 2 + 1) * 64]);
                f32x4 cA = MFMA16(w20, h1A0, b2rv[t]);
                a2A[t]   = MFMA16(w21, h1A1, cA);
                f32x4 cB = MFMA16(w20, h1B0, b2rv[t]);
                a2B[t]   = MFMA16(w21, h1B1, cB);
            }

            cd_pack(a2A, lA, hA);
            cd_pack(a2B, lB, hB);
            bf16x8 h2A0 = as_frag(lA), h2A1 = as_frag(hA);
            bf16x8 h2B0 = as_frag(lB), h2B1 = as_frag(hB);

            f32x4 cb = {b3r, b3r, b3r, b3r};
            f32x4 acc3A = MFMA16(h2A1, w3f[1], MFMA16(h2A0, w3f[0], cb));
            f32x4 acc3B = MFMA16(h2B1, w3f[1], MFMA16(h2B0, w3f[0], cb));

            float oA0 = sigmoid_fast(acc3A[0]), oA1 = sigmoid_fast(acc3A[1]);
            float oA2 = sigmoid_fast(acc3A[2]), oA3 = sigmoid_fast(acc3A[3]);
            float oB0 = sigmoid_fast(acc3B[0]), oB1 = sigmoid_fast(acc3B[1]);
            float oB2 = sigmoid_fast(acc3B[2]), oB3 = sigmoid_fast(acc3B[3]);
            if (nn < 3) {
                float* oa = (float*)(ob + (2*sp)     * 48 + oofs);
                float* obp= (float*)(ob + (2*sp + 1) * 48 + oofs);
                oa[0] = oA0; oa[3] = oA1; oa[6] = oA2; oa[9] = oA3;
                obp[0] = oB0; obp[3] = oB1; obp[6] = oB2; obp[9] = oB3;
            }
        };

        do_pair(0);

        // ---- stage B: hash from prefetched pos, issue emb gather
        {
            int s0 = (int)(q0 * 8.0f), s1 = (int)(q1 * 8.0f), s2 = (int)(q2 * 8.0f);
            uint32_t h = ((uint32_t)s0 * 73856093u) ^ ((uint32_t)s1 * 19349663u) ^
                         ((uint32_t)s2 * 83492791u);
            uint32_t idx = h & 32767u;
            f0 = emb4[idx*4+0]; f1 = emb4[idx*4+1];
            f2 = emb4[idx*4+2]; f3 = emb4[idx*4+3];
        }

        do_pair(1);

        cfence();   // next tile's xbuf writes stay behind this tile's reads
    }
}

extern "C" void kernel_launch(void* const* d_in, const int* in_sizes, int n_in,
                              void* d_out, int out_size, void* d_ws, size_t ws_size,
                              hipStream_t stream) {
    const float* pos = (const float*)d_in[0];
    const float* nrm = (const float*)d_in[1];
    const float* emb = (const float*)d_in[2];
    const float* W1  = (const float*)d_in[3];
    const float* b1  = (const float*)d_in[4];
    const float* W2  = (const float*)d_in[5];
    const float* b2  = (const float*)d_in[6];
    const float* W3  = (const float*)d_in[7];
    const float* b3  = (const float*)d_in[8];
    float* out = (float*)d_out;
    float* ws  = (float*)d_ws;   // 896 int4 = 14336 B used

    int n = in_sizes[0] / 3;      // 2,097,152
    int ntiles = n / 64;          // 32768

    nrad_setup_kernel<<<1, 256, 0, stream>>>(W1, b1, W2, W3, ws);
    nrad_mfma_kernel<<<2048, 256, 0, stream>>>(pos, nrm, emb, b2, b3, ws,
                                               out, ntiles);
}

// Round 15
// 138.959 us; speedup vs baseline: 1.0439x; 1.0143x over previous
//
#include <hip/hip_runtime.h>
#include <cstdint>

// NeuralRadiance via bf16 MFMA (16x16x32). Round 15 = round 14 (verified
// best, ~52.6us) + two epilogue/register cuts:
//  (a) L3 TRANSPOSED: out^T = W3T @ h2^T. The existing w3 fragment works
//      unchanged as the A operand (A[m][k] lane layout == B[k][n] layout):
//      A~[m=ch][k] = W3[Lam(k)][ch]; packed h2-D reinterpreted as B gives
//      B~[k][n=pt] = h2[Lam(k)][pt]; Lam telescopes -> true dot product.
//      D: lane(q,nn) reg r = channel q*4+r of point nn -> q==0 lanes hold a
//      point's 3 channels in regs 0..2: 3 sigmoids (was 4) and ONE
//      contiguous 12B store per point (8 store insts/tile, was 16).
//      C-init: {b3[0..2],0} on q==0 lanes.
//  (b) b2 C-init streamed from LDS (broadcast ds_read_b128, same-address
//      across nn lanes = conflict-free) instead of 16 persistent VGPRs.
// Keeps: jammed 2-sub pairs, Lam-permuted weights, W2 frags in LDS, staged
// prefetch, xbuf constant-region hoist, grid 2048, launch_bounds(256,3).
// relu stays float-domain fmaxf (packed-int relu NaN'd twice: r12, r13).

typedef short  bf16x8 __attribute__((ext_vector_type(8)));
typedef float  f32x4  __attribute__((ext_vector_type(4)));

#define MFMA16(A, B, C) __builtin_amdgcn_mfma_f32_16x16x32_bf16((A), (B), (C), 0, 0, 0)

// guaranteed-HW packed cvt: 2 f32 -> dword of 2 bf16 (lo=a, hi=b), RNE
__device__ inline int pk(float a, float b) {
    int d;
    __asm__("v_cvt_pk_bf16_f32 %0, %1, %2" : "=v"(d) : "v"(a), "v"(b));
    return d;
}

// compile-time ordering only (DS pipe is in-order per wave; validated r4-r14)
__device__ inline void cfence() { __asm__ volatile("" ::: "memory"); }

__device__ inline float sigmoid_fast(float x) {
    float e = __expf(-x);
    return __builtin_amdgcn_rcpf(1.0f + e);
}

// logical feature held at k-position k of the packed-D fragment
__device__ inline int lam(int k) {
    return 32 * (k >> 5) + 16 * ((k >> 2) & 1) + 4 * ((k >> 3) & 3) + (k & 3);
}

// C/D accs (4x f32x4) -> next-layer frag halves: float relu + pack (verified).
__device__ inline void cd_pack(const f32x4 acc[4], int4& lo, int4& hi) {
    lo = make_int4(pk(fmaxf(acc[0][0],0.f), fmaxf(acc[0][1],0.f)),
                   pk(fmaxf(acc[0][2],0.f), fmaxf(acc[0][3],0.f)),
                   pk(fmaxf(acc[1][0],0.f), fmaxf(acc[1][1],0.f)),
                   pk(fmaxf(acc[1][2],0.f), fmaxf(acc[1][3],0.f)));
    hi = make_int4(pk(fmaxf(acc[2][0],0.f), fmaxf(acc[2][1],0.f)),
                   pk(fmaxf(acc[2][2],0.f), fmaxf(acc[2][3],0.f)),
                   pk(fmaxf(acc[3][0],0.f), fmaxf(acc[3][1],0.f)),
                   pk(fmaxf(acc[3][2],0.f), fmaxf(acc[3][3],0.f)));
}

__device__ inline bf16x8 as_frag(int4 v) {
    bf16x8 f; __builtin_memcpy(&f, &v, sizeof(f)); return f;
}

#define XS 40   // xbuf row stride in shorts (20 dwords; b128 at bank floor)

// ---- setup: fragment-ordered bf16 weights in ws (int4 units):
//   ws[0..255]   : w1 frags [t*64+lane]          (identity out-feats)
//   ws[256..767] : w2 frags [(t*2+ks)*64+lane]   (input rows permuted by lam)
//   ws[768..895] : w3 frags [h*64+lane]          (input rows permuted by lam)
__global__ __launch_bounds__(256) void nrad_setup_kernel(
    const float* __restrict__ W1, const float* __restrict__ b1,
    const float* __restrict__ W2, const float* __restrict__ W3,
    float* __restrict__ ws)
{
    const int tid  = threadIdx.x;
    const int wv   = tid >> 6;
    const int lane = tid & 63;
    const int q    = lane >> 4;
    const int nn   = lane & 15;
    int4* w1o = (int4*)ws;
    int4* w2o = (int4*)ws + 256;
    int4* w3o = (int4*)ws + 768;

    if (wv == 0) {
        // A-frag of W1T tile t: A[m=nn][k=q*8+j]; k<19=W1, k==19=b1, else 0
        for (int t = 0; t < 4; ++t) {
            int n = t * 16 + nn;
            float v[8];
            #pragma unroll
            for (int j = 0; j < 8; ++j) {
                int k = q * 8 + j;
                v[j] = (k < 19) ? W1[k * 64 + n] : (k == 19 ? b1[n] : 0.0f);
            }
            w1o[t * 64 + lane] = make_int4(pk(v[0],v[1]), pk(v[2],v[3]),
                                           pk(v[4],v[5]), pk(v[6],v[7]));
        }
    } else if (wv == 3) {
        // W3 fragment (rows permuted by lam; cols zero-padded past 3).
        // Same data serves as A operand of W3T in the transposed L3.
        for (int h = 0; h < 2; ++h) {
            float v[8];
            #pragma unroll
            for (int j = 0; j < 8; ++j) {
                int kin = lam(h * 32 + q * 8 + j);
                v[j] = (nn < 3) ? W3[kin * 3 + nn] : 0.0f;
            }
            w3o[h * 64 + lane] = make_int4(pk(v[0],v[1]), pk(v[2],v[3]),
                                           pk(v[4],v[5]), pk(v[6],v[7]));
        }
    } else {
        // A-frag of W2T tile (t,ks): A[m=nn][k] = W2[lam(k)][t*16+nn]
        for (int tt = 0; tt < 2; ++tt) {
            int t = (wv - 1) * 2 + tt;
            int n = t * 16 + nn;
            for (int ks = 0; ks < 2; ++ks) {
                float v[8];
                #pragma unroll
                for (int j = 0; j < 8; ++j) {
                    int kin = lam(ks * 32 + q * 8 + j);
                    v[j] = W2[kin * 64 + n];
                }
                w2o[(t * 2 + ks) * 64 + lane] = make_int4(pk(v[0],v[1]), pk(v[2],v[3]),
                                                          pk(v[4],v[5]), pk(v[6],v[7]));
            }
        }
    }
}

__global__ __launch_bounds__(256, 3) void nrad_mfma_kernel(
    const float* __restrict__ pos, const float* __restrict__ nrm,
    const float* __restrict__ emb,
    const float* __restrict__ b2, const float* __restrict__ b3,
    const float* __restrict__ ws, float* __restrict__ out, int ntiles)
{
    // w2lds: 8 frags x 64 lanes x 16B = 8KB [frag][lane] (conflict-free);
    // b2lds: 64 floats (broadcast reads); xbuf: per-wave x staging.
    __shared__ alignas(16) int4  w2lds[512];
    __shared__ alignas(16) float b2lds[64];
    __shared__ alignas(16) short xbuf[4][64 * XS];

    const int tid  = threadIdx.x;
    const int wave = tid >> 6;
    const int lane = tid & 63;
    const int q    = lane >> 4;
    const int nn   = lane & 15;

    // ---- stage W2 fragments + b2 into LDS
    const int4* wsf = (const int4*)ws;
    w2lds[tid]       = wsf[256 + tid];
    w2lds[tid + 256] = wsf[512 + tid];
    if (tid < 64) b2lds[tid] = b2[tid];
    __syncthreads();

    // ---- register fragments: w1, w3 (w2/b2 stream from LDS)
    bf16x8 w1f[4], w3f[2];
    #pragma unroll
    for (int t = 0; t < 4; ++t) w1f[t] = as_frag(wsf[t * 64 + lane]);
    w3f[0] = as_frag(wsf[768 + lane]);
    w3f[1] = as_frag(wsf[832 + lane]);
    // L3-transposed C init: reg r = b3[q*4+r], nonzero only for q==0, r<3
    f32x4 cb3;
    {
        float t0 = b3[0], t1 = b3[1], t2 = b3[2];
        cb3[0] = (q == 0) ? t0 : 0.0f;
        cb3[1] = (q == 0) ? t1 : 0.0f;
        cb3[2] = (q == 0) ? t2 : 0.0f;
        cb3[3] = 0.0f;
    }

    short* xw = &xbuf[wave][0];
    const int4* w2l = w2lds + lane;      // + (t*2+ks)*64
    const int xro  = nn * XS + q * 8;    // + sub*16*XS : L1 B-frag read

    // ---- one-time: zero the constant region of this wave's xbuf rows
    {
        int* zp = (int*)(xw + lane * XS);
        zp[10] = 0; zp[11] = 0;
        *(int4*)(xw + lane * XS + 24) = make_int4(0, 0, 0, 0);
    }

    const int wave_gid = blockIdx.x * 4 + wave;
    const int nwaves   = gridDim.x * 4;
    const float4* emb4 = (const float4*)emb;

    // ---- prefetch state (loop-carried): normal + gathered embedding
    float n0 = 0, n1 = 0, n2 = 0;
    float4 f0{}, f1{}, f2{}, f3{};
    if (wave_gid < ntiles) {
        int i = wave_gid * 64 + lane;
        float p0 = pos[3*i], p1 = pos[3*i+1], p2 = pos[3*i+2];
        n0 = nrm[3*i]; n1 = nrm[3*i+1]; n2 = nrm[3*i+2];
        int s0 = (int)(p0 * 8.0f), s1 = (int)(p1 * 8.0f), s2 = (int)(p2 * 8.0f);
        uint32_t h = ((uint32_t)s0 * 73856093u) ^ ((uint32_t)s1 * 19349663u) ^
                     ((uint32_t)s2 * 83492791u);
        uint32_t idx = h & 32767u;
        f0 = emb4[idx*4+0]; f1 = emb4[idx*4+1];
        f2 = emb4[idx*4+2]; f3 = emb4[idx*4+3];
    }

    for (int tile = wave_gid; tile < ntiles; tile += nwaves) {
        const int base = tile * 64;
        const float* ob = out + (size_t)base * 3;
        const f32x4 z = {0.0f, 0.0f, 0.0f, 0.0f};

        // ---- pack prefetched point into xbuf row = lane (A,B,C only)
        {
            int4 A = make_int4(pk(f0.x, f0.y), pk(f0.z, f0.w), pk(f1.x, f1.y), pk(f1.z, f1.w));
            int4 B = make_int4(pk(f2.x, f2.y), pk(f2.z, f2.w), pk(f3.x, f3.y), pk(f3.z, f3.w));
            int2 C = make_int2(pk(n0, n1), pk(n2, 1.0f));   // k=19 -> 1.0 (bias)
            int4* xr = (int4*)(xw + lane * XS);
            xr[0] = A; xr[1] = B;
            *(int2*)(xw + lane * XS + 16) = C;
        }
        cfence();

        // ---- stage A: issue next tile's pos/nrm loads
        int nt = tile + nwaves;
        int lt = (nt < ntiles) ? nt : tile;   // wave-uniform clamp
        int inext = lt * 64 + lane;
        float q0 = pos[3*inext], q1 = pos[3*inext+1], q2 = pos[3*inext+2];
        n0 = nrm[3*inext]; n1 = nrm[3*inext+1]; n2 = nrm[3*inext+2];

        // ---- one jammed sub-pair (subs 2sp, 2sp+1): two independent chains
        auto do_pair = [&](int sp) {
            bf16x8 xfA = *(const bf16x8*)(xw + (2*sp)     * 16 * XS + xro);
            bf16x8 xfB = *(const bf16x8*)(xw + (2*sp + 1) * 16 * XS + xro);

            f32x4 a1A[4], a1B[4];
            #pragma unroll
            for (int t = 0; t < 4; ++t) a1A[t] = MFMA16(w1f[t], xfA, z);
            #pragma unroll
            for (int t = 0; t < 4; ++t) a1B[t] = MFMA16(w1f[t], xfB, z);

            int4 lA, hA, lB, hB;
            cd_pack(a1A, lA, hA);
            cd_pack(a1B, lB, hB);
            bf16x8 h1A0 = as_frag(lA), h1A1 = as_frag(hA);
            bf16x8 h1B0 = as_frag(lB), h1B1 = as_frag(hB);

            f32x4 a2A[4], a2B[4];
            #pragma unroll
            for (int t = 0; t < 4; ++t) {
                bf16x8 w20 = as_frag(w2l[(t * 2 + 0) * 64]);
                bf16x8 w21 = as_frag(w2l[(t * 2 + 1) * 64]);
                f32x4 c0 = *(const f32x4*)(b2lds + t * 16 + q * 4);  // broadcast
                f32x4 cA = MFMA16(w20, h1A0, c0);
                a2A[t]   = MFMA16(w21, h1A1, cA);
                f32x4 cB = MFMA16(w20, h1B0, c0);
                a2B[t]   = MFMA16(w21, h1B1, cB);
            }

            cd_pack(a2A, lA, hA);
            cd_pack(a2B, lB, hB);
            bf16x8 h2A0 = as_frag(lA), h2A1 = as_frag(hA);
            bf16x8 h2B0 = as_frag(lB), h2B1 = as_frag(hB);

            // ---- L3 transposed: D[m=channel][n=point]; A = w3f (W3T), B = h2
            f32x4 acc3A = MFMA16(w3f[1], h2A1, MFMA16(w3f[0], h2A0, cb3));
            f32x4 acc3B = MFMA16(w3f[1], h2B1, MFMA16(w3f[0], h2B0, cb3));

            // ---- sigmoid (3 live channels) + contiguous 12B store per point
            float sA0 = sigmoid_fast(acc3A[0]), sA1 = sigmoid_fast(acc3A[1]);
            float sA2 = sigmoid_fast(acc3A[2]);
            float sB0 = sigmoid_fast(acc3B[0]), sB1 = sigmoid_fast(acc3B[1]);
            float sB2 = sigmoid_fast(acc3B[2]);
            if (q == 0) {
                float* oa  = (float*)(ob + (2*sp)     * 48 + nn * 3);
                float* obp = (float*)(ob + (2*sp + 1) * 48 + nn * 3);
                oa[0] = sA0;  oa[1] = sA1;  oa[2] = sA2;
                obp[0] = sB0; obp[1] = sB1; obp[2] = sB2;
            }
        };

        do_pair(0);

        // ---- stage B: hash from prefetched pos, issue emb gather
        {
            int s0 = (int)(q0 * 8.0f), s1 = (int)(q1 * 8.0f), s2 = (int)(q2 * 8.0f);
            uint32_t h = ((uint32_t)s0 * 73856093u) ^ ((uint32_t)s1 * 19349663u) ^
                         ((uint32_t)s2 * 83492791u);
            uint32_t idx = h & 32767u;
            f0 = emb4[idx*4+0]; f1 = emb4[idx*4+1];
            f2 = emb4[idx*4+2]; f3 = emb4[idx*4+3];
        }

        do_pair(1);

        cfence();   // next tile's xbuf writes stay behind this tile's reads
    }
}

extern "C" void kernel_launch(void* const* d_in, const int* in_sizes, int n_in,
                              void* d_out, int out_size, void* d_ws, size_t ws_size,
                              hipStream_t stream) {
    const float* pos = (const float*)d_in[0];
    const float* nrm = (const float*)d_in[1];
    const float* emb = (const float*)d_in[2];
    const float* W1  = (const float*)d_in[3];
    const float* b1  = (const float*)d_in[4];
    const float* W2  = (const float*)d_in[5];
    const float* b2  = (const float*)d_in[6];
    const float* W3  = (const float*)d_in[7];
    const float* b3  = (const float*)d_in[8];
    float* out = (float*)d_out;
    float* ws  = (float*)d_ws;   // 896 int4 = 14336 B used

    int n = in_sizes[0] / 3;      // 2,097,152
    int ntiles = n / 64;          // 32768

    nrad_setup_kernel<<<1, 256, 0, stream>>>(W1, b1, W2, W3, ws);
    nrad_mfma_kernel<<<2048, 256, 0, stream>>>(pos, nrm, emb, b2, b3, ws,
                                               out, ntiles);
}